// Round 1
// baseline (485.676 us; speedup 1.0000x reference)
//
#include <hip/hip_runtime.h>
#include <cstdint>
#include <cstddef>

// Problem constants (fixed by reference)
#define BB 32
#define NN 8192
#define DIN 64
#define DOUT 128
#define NR 4
#define BN_EPS 1e-5f

#define SEGS 8  // point segments per (b, ring) bucket in compute kernel

// Workspace layout (needs ~2.2 MB):
//   [0, 512)           int   counts[B*NR]      (memset 0 each launch)
//   [512, 66048)       uint  smax_keys[B*NR*DOUT] (memset 0 == -NaN key, acts as -inf)
//   [66560, ...)       u16   buckets[B*NR*NN]  (2 MB, no init needed)
#define WS_KEYS_OFF 512
#define WS_BUCKETS_OFF 66560

// ---------------------------------------------------------------------------
// K1: bucket points by (batch, ring). Wave-aggregated atomics: 4 atomics per
// wave-iteration instead of 64.
__global__ void k_bucket(const int* __restrict__ ring, int* __restrict__ counts,
                         unsigned short* __restrict__ buckets) {
  const int b = blockIdx.y;
  const int n0 = blockIdx.x * 2048;
  const int lane = threadIdx.x & 63;
#pragma unroll
  for (int k = 0; k < 8; ++k) {
    const int n = n0 + k * 256 + (int)threadIdx.x;
    const int r = ring[b * NN + n];
    unsigned long long mym = 0ull;
#pragma unroll
    for (int rr = 0; rr < NR; ++rr) {
      unsigned long long mr = __ballot(r == rr);
      if (r == rr) mym = mr;
    }
    const int leader = __ffsll((unsigned long long)mym) - 1;
    const int cnt = __popcll(mym);
    const int pos_in = __popcll(mym & ((1ull << lane) - 1ull));
    int base = 0;
    if (lane == leader) base = atomicAdd(&counts[b * NR + r], cnt);
    base = __shfl(base, leader, 64);
    buckets[(b * NR + r) * NN + base + pos_in] = (unsigned short)n;
  }
}

// ---------------------------------------------------------------------------
// K2: per-(b, ring, o-tile, segment) block computes running max of raw dots.
// Ring is block-uniform => W loads are wave-uniform (scalar loads expected).
// Each thread holds its point's x[64] in VGPRs, reused across 32 output chans.
__global__ void k_compute(const float* __restrict__ x, const float* __restrict__ W,
                          const int* __restrict__ counts,
                          const unsigned short* __restrict__ buckets,
                          unsigned int* __restrict__ smax_keys) {
  const int seg = blockIdx.x;
  const int r = blockIdx.y & (NR - 1);
  const int ot = blockIdx.y >> 2;  // o-tile of 32 channels
  const int b = blockIdx.z;
  const int count = counts[b * NR + r];
  const unsigned short* bk = buckets + (size_t)(b * NR + r) * NN;
  const float* xb = x + (size_t)b * DIN * NN;
  const float* Wr = W + (size_t)(r * DOUT + ot * 32) * DIN;

  float maxacc[32];
#pragma unroll
  for (int i = 0; i < 32; ++i) maxacc[i] = -INFINITY;

  for (int i = seg * 256 + (int)threadIdx.x; i < count; i += SEGS * 256) {
    const int n = bk[i];
    float xr[DIN];
#pragma unroll
    for (int d = 0; d < DIN; ++d) xr[d] = xb[(size_t)d * NN + n];
#pragma unroll
    for (int oo = 0; oo < 32; ++oo) {
      const float* w = Wr + oo * DIN;
      float a0 = 0.f, a1 = 0.f;  // two partial sums for FMA-latency ILP
#pragma unroll
      for (int d = 0; d < DIN; d += 2) {
        a0 = fmaf(w[d], xr[d], a0);
        a1 = fmaf(w[d + 1], xr[d + 1], a1);
      }
      maxacc[oo] = fmaxf(maxacc[oo], a0 + a1);
    }
  }

  // 64-lane butterfly max per channel
#pragma unroll
  for (int oo = 0; oo < 32; ++oo) {
    float v = maxacc[oo];
#pragma unroll
    for (int k = 32; k >= 1; k >>= 1) v = fmaxf(v, __shfl_xor(v, k, 64));
    maxacc[oo] = v;
  }

  __shared__ float wred[4][32];
  const int wave = threadIdx.x >> 6;
  const int lane = threadIdx.x & 63;
  if (lane == 0) {
#pragma unroll
    for (int oo = 0; oo < 32; ++oo) wred[wave][oo] = maxacc[oo];
  }
  __syncthreads();
  if (threadIdx.x < 32) {
    const float v = fmaxf(fmaxf(wred[0][threadIdx.x], wred[1][threadIdx.x]),
                          fmaxf(wred[2][threadIdx.x], wred[3][threadIdx.x]));
    // order-preserving float->uint key so atomicMax(uint) == float max
    const unsigned int u = __float_as_uint(v);
    const unsigned int key = (u & 0x80000000u) ? ~u : (u | 0x80000000u);
    atomicMax(&smax_keys[(size_t)(b * NR + r) * DOUT + ot * 32 + threadIdx.x], key);
  }
}

// ---------------------------------------------------------------------------
// K3: finalize affine on the 16K maxima (in LDS), then broadcast to output:
// out[b][o][n] = ymax[b][ring[b,n]][o]. float4 stores along n.
__global__ void k_out(const float* __restrict__ bias, const float* __restrict__ gamma,
                      const float* __restrict__ beta, const float* __restrict__ mean,
                      const float* __restrict__ var, const int* __restrict__ ring,
                      const unsigned int* __restrict__ smax_keys,
                      float* __restrict__ out) {
  const int b = blockIdx.y;
  const int n0 = blockIdx.x * 1024;

  __shared__ float ymax[NR * DOUT];
  for (int t = threadIdx.x; t < NR * DOUT; t += 256) {
    const unsigned int key = smax_keys[(size_t)b * NR * DOUT + t];
    const unsigned int u = (key & 0x80000000u) ? (key ^ 0x80000000u) : ~key;
    const float raw = __uint_as_float(u);
    const float sc = gamma[t] * rsqrtf(var[t] + BN_EPS);
    ymax[t] = (raw + bias[t] - mean[t]) * sc + beta[t];
  }
  __syncthreads();

  const int n = n0 + (int)threadIdx.x * 4;
  const int4 rg = *(const int4*)&ring[(size_t)b * NN + n];
#pragma unroll 8
  for (int o = 0; o < DOUT; ++o) {
    float4 v;
    v.x = ymax[rg.x * DOUT + o];
    v.y = ymax[rg.y * DOUT + o];
    v.z = ymax[rg.z * DOUT + o];
    v.w = ymax[rg.w * DOUT + o];
    *(float4*)&out[((size_t)b * DOUT + o) * NN + n] = v;
  }
}

// ---------------------------------------------------------------------------
extern "C" void kernel_launch(void* const* d_in, const int* in_sizes, int n_in,
                              void* d_out, int out_size, void* d_ws, size_t ws_size,
                              hipStream_t stream) {
  const float* x = (const float*)d_in[0];
  const int* ring = (const int*)d_in[1];
  const float* W = (const float*)d_in[2];
  const float* bias = (const float*)d_in[3];
  const float* gamma = (const float*)d_in[4];
  const float* beta = (const float*)d_in[5];
  const float* mean = (const float*)d_in[6];
  const float* var = (const float*)d_in[7];
  float* out = (float*)d_out;

  char* ws = (char*)d_ws;
  int* counts = (int*)(ws + 0);
  unsigned int* keys = (unsigned int*)(ws + WS_KEYS_OFF);
  unsigned short* buckets = (unsigned short*)(ws + WS_BUCKETS_OFF);

  // zero counts + smax keys (key 0 decodes to -NaN, i.e. identity for max)
  hipMemsetAsync(ws, 0, WS_KEYS_OFF + (size_t)BB * NR * DOUT * 4, stream);

  k_bucket<<<dim3(NN / 2048, BB), 256, 0, stream>>>(ring, counts, buckets);
  k_compute<<<dim3(SEGS, NR * 4, BB), 256, 0, stream>>>(x, W, counts, buckets, keys);
  k_out<<<dim3(NN / 1024, BB), 256, 0, stream>>>(bias, gamma, beta, mean, var, ring,
                                                 keys, out);
}

// Round 2
// 384.797 us; speedup vs baseline: 1.2622x; 1.2622x over previous
//
#include <hip/hip_runtime.h>
#include <cstdint>
#include <cstddef>

// Problem constants (fixed by reference)
#define BB 32
#define NN 8192
#define DIN 64
#define DOUT 128
#define NR 4
#define BN_EPS 1e-5f

#define SEGS 2  // point segments per (b, ring, o-tile) bucket in compute kernel

// Workspace layout (needs ~2.2 MB):
//   [0, 512)           int   counts[B*NR]      (memset 0 each launch)
//   [512, 66048)       uint  smax_keys[B*NR*DOUT] (memset 0 == -NaN key, acts as -inf)
//   [66560, ...)       u16   buckets[B*NR*NN]  (2 MB, no init needed)
#define WS_KEYS_OFF 512
#define WS_BUCKETS_OFF 66560

// ---------------------------------------------------------------------------
// K1: bucket points by (batch, ring). Wave-aggregated atomics: 4 atomics per
// wave-iteration instead of 64.
__global__ void k_bucket(const int* __restrict__ ring, int* __restrict__ counts,
                         unsigned short* __restrict__ buckets) {
  const int b = blockIdx.y;
  const int n0 = blockIdx.x * 1024;
  const int lane = threadIdx.x & 63;
#pragma unroll
  for (int k = 0; k < 4; ++k) {
    const int n = n0 + k * 256 + (int)threadIdx.x;
    const int r = ring[b * NN + n];
    unsigned long long mym = 0ull;
#pragma unroll
    for (int rr = 0; rr < NR; ++rr) {
      unsigned long long mr = __ballot(r == rr);
      if (r == rr) mym = mr;
    }
    const int leader = __ffsll((unsigned long long)mym) - 1;
    const int cnt = __popcll(mym);
    const int pos_in = __popcll(mym & ((1ull << lane) - 1ull));
    int base = 0;
    if (lane == leader) base = atomicAdd(&counts[b * NR + r], cnt);
    base = __shfl(base, leader, 64);
    buckets[(b * NR + r) * NN + base + pos_in] = (unsigned short)n;
  }
}

// ---------------------------------------------------------------------------
// K2: per-(b, ring, o-tile, segment) block computes running max of raw dots.
// Ring is block-uniform => W loads are wave-uniform (scalar loads expected).
// Each thread holds its point's x[64] in VGPRs, reused across 32 output chans.
// SEGS=2 => ~4 points per thread: amortizes the butterfly/atomic tail and
// lets the gathered x loads pipeline across point iterations.
__global__ void __launch_bounds__(256) k_compute(
    const float* __restrict__ x, const float* __restrict__ W,
    const int* __restrict__ counts, const unsigned short* __restrict__ buckets,
    unsigned int* __restrict__ smax_keys) {
  const int seg = blockIdx.x;
  const int r = blockIdx.y & (NR - 1);
  const int ot = blockIdx.y >> 2;  // o-tile of 32 channels
  const int b = blockIdx.z;
  const int count = counts[b * NR + r];
  const unsigned short* bk = buckets + (size_t)(b * NR + r) * NN;
  const float* xb = x + (size_t)b * DIN * NN;
  const float* Wr = W + (size_t)(r * DOUT + ot * 32) * DIN;

  float maxacc[32];
#pragma unroll
  for (int i = 0; i < 32; ++i) maxacc[i] = -INFINITY;

  for (int i = seg * 256 + (int)threadIdx.x; i < count; i += SEGS * 256) {
    const int n = bk[i];
    float xr[DIN];
#pragma unroll
    for (int d = 0; d < DIN; ++d) xr[d] = xb[(size_t)d * NN + n];
#pragma unroll
    for (int oo = 0; oo < 32; ++oo) {
      const float* w = Wr + oo * DIN;
      float a0 = 0.f, a1 = 0.f;  // two partial sums for FMA-latency ILP
#pragma unroll
      for (int d = 0; d < DIN; d += 2) {
        a0 = fmaf(w[d], xr[d], a0);
        a1 = fmaf(w[d + 1], xr[d + 1], a1);
      }
      maxacc[oo] = fmaxf(maxacc[oo], a0 + a1);
    }
  }

  // 64-lane butterfly max per channel
#pragma unroll
  for (int oo = 0; oo < 32; ++oo) {
    float v = maxacc[oo];
#pragma unroll
    for (int k = 32; k >= 1; k >>= 1) v = fmaxf(v, __shfl_xor(v, k, 64));
    maxacc[oo] = v;
  }

  __shared__ float wred[4][32];
  const int wave = threadIdx.x >> 6;
  const int lane = threadIdx.x & 63;
  if (lane == 0) {
#pragma unroll
    for (int oo = 0; oo < 32; ++oo) wred[wave][oo] = maxacc[oo];
  }
  __syncthreads();
  if (threadIdx.x < 32) {
    const float v = fmaxf(fmaxf(wred[0][threadIdx.x], wred[1][threadIdx.x]),
                          fmaxf(wred[2][threadIdx.x], wred[3][threadIdx.x]));
    // order-preserving float->uint key so atomicMax(uint) == float max
    const unsigned int u = __float_as_uint(v);
    const unsigned int key = (u & 0x80000000u) ? ~u : (u | 0x80000000u);
    atomicMax(&smax_keys[(size_t)(b * NR + r) * DOUT + ot * 32 + threadIdx.x], key);
  }
}

// ---------------------------------------------------------------------------
// K3: finalize affine on the 16K maxima, then broadcast to output:
// out[b][o][n] = ymax[b][ring[b,n]][o]. float4 stores along n.
// LDS table transposed to [o][r] so the 4 ring addresses hit 4 DIFFERENT
// banks (old [r][o] layout: r*128+o all alias to bank o%32 => 4-way conflict).
// Grid split over o-groups too: 1024 blocks to saturate write BW.
__global__ void k_out(const float* __restrict__ bias, const float* __restrict__ gamma,
                      const float* __restrict__ beta, const float* __restrict__ mean,
                      const float* __restrict__ var, const int* __restrict__ ring,
                      const unsigned int* __restrict__ smax_keys,
                      float* __restrict__ out) {
  const int b = blockIdx.z;
  const int og = blockIdx.y;  // 32-channel group
  const int n0 = blockIdx.x * 1024;

  __shared__ float ymax[32 * NR];  // [oo][r]
  if (threadIdx.x < 32 * NR) {
    const int oo = (int)threadIdx.x >> 2;
    const int r = (int)threadIdx.x & 3;
    const int o = og * 32 + oo;
    const int t = r * DOUT + o;
    const unsigned int key = smax_keys[(size_t)b * NR * DOUT + t];
    const unsigned int u = (key & 0x80000000u) ? (key ^ 0x80000000u) : ~key;
    const float raw = __uint_as_float(u);
    const float sc = gamma[t] * rsqrtf(var[t] + BN_EPS);
    ymax[oo * NR + r] = (raw + bias[t] - mean[t]) * sc + beta[t];
  }
  __syncthreads();

  const int n = n0 + (int)threadIdx.x * 4;
  const int4 rg = *(const int4*)&ring[(size_t)b * NN + n];
#pragma unroll 8
  for (int oo = 0; oo < 32; ++oo) {
    const int o = og * 32 + oo;
    float4 v;
    v.x = ymax[oo * NR + rg.x];
    v.y = ymax[oo * NR + rg.y];
    v.z = ymax[oo * NR + rg.z];
    v.w = ymax[oo * NR + rg.w];
    *(float4*)&out[((size_t)b * DOUT + o) * NN + n] = v;
  }
}

// ---------------------------------------------------------------------------
extern "C" void kernel_launch(void* const* d_in, const int* in_sizes, int n_in,
                              void* d_out, int out_size, void* d_ws, size_t ws_size,
                              hipStream_t stream) {
  const float* x = (const float*)d_in[0];
  const int* ring = (const int*)d_in[1];
  const float* W = (const float*)d_in[2];
  const float* bias = (const float*)d_in[3];
  const float* gamma = (const float*)d_in[4];
  const float* beta = (const float*)d_in[5];
  const float* mean = (const float*)d_in[6];
  const float* var = (const float*)d_in[7];
  float* out = (float*)d_out;

  char* ws = (char*)d_ws;
  int* counts = (int*)(ws + 0);
  unsigned int* keys = (unsigned int*)(ws + WS_KEYS_OFF);
  unsigned short* buckets = (unsigned short*)(ws + WS_BUCKETS_OFF);

  // zero counts + smax keys (key 0 decodes to -NaN, i.e. identity for max)
  hipMemsetAsync(ws, 0, WS_KEYS_OFF + (size_t)BB * NR * DOUT * 4, stream);

  k_bucket<<<dim3(NN / 1024, BB), 256, 0, stream>>>(ring, counts, buckets);
  k_compute<<<dim3(SEGS, NR * 4, BB), 256, 0, stream>>>(x, W, counts, buckets, keys);
  k_out<<<dim3(NN / 1024, DOUT / 32, BB), 256, 0, stream>>>(bias, gamma, beta, mean,
                                                            var, ring, keys, out);
}